// Round 9
// baseline (313.113 us; speedup 1.0000x reference)
//
#include <hip/hip_runtime.h>

// R8 wave-pair k-split, with the barrier pathology removed:
//  - ALL in-loop barriers are raw {s_waitcnt lgkmcnt(0); s_barrier} — the
//    vmcnt(0) drain in __syncthreads forced every wave to wait for all
//    outstanding global flush-stores EVERY step (R8: 119->151us regression).
//    LDS ordering is all the exchange/window logic needs; global stores
//    retire on their own.
//  - Exchange double-buffered (2x1280 floats) -> ONE barrier per step.
//    Safety: step t reads buf[t&1]; the next write of that buffer is at
//    step t+2, which every wave reaches only after passing step t+1's
//    barrier, which it reaches only after its own step-t reads completed
//    (lgkmcnt(0) inside the fused barrier). No read-after-overwrite.
//  - Weight/input staging overlapped with the window region -> LDS 18.9 KB
//    -> 8 blocks/CU = 32 waves/CU resident (grid = 2048 blocks = 8/CU).
// Numerics identical to the passing R8 (same summation order).

constexpr int kB     = 262144;
constexpr int kSteps = 15;
constexpr int PAD    = 17;             // window row stride
constexpr int RPB    = 128;            // rows per block
constexpr int WIN    = RPB * PAD;      // 2176 floats
constexpr int XOFF   = WIN;            // exchange: 2 buffers x 1280 floats
constexpr int LDSZ   = WIN + 2 * 1280; // 4736 floats = 18.9 KB
constexpr int ISTG   = 0;              // input staging [0..2304) (pre-loop)
constexpr int WSTG   = 2304;           // weight staging [2304..2624) (pre-loop)

__device__ __forceinline__ float relu_(float v) { return fmaxf(v, 0.0f); }
__device__ __forceinline__ float sigmoid_(float v) {
    return __builtin_amdgcn_rcpf(1.0f + __expf(-v));
}
__device__ __forceinline__ float rl_(float v, int lane) {
    return __int_as_float(__builtin_amdgcn_readlane(__float_as_int(v), lane));
}
// lgkm-only barrier: orders LDS, does NOT drain global stores.
__device__ __forceinline__ void bar_lgkm() {
    asm volatile("s_waitcnt lgkmcnt(0)\n\ts_barrier" ::: "memory");
}

__global__ __launch_bounds__(256) void Program_4578435138231_kernel(
    const float* __restrict__ x,
    const float* __restrict__ c1w, const float* __restrict__ c1b,
    const float* __restrict__ c2w, const float* __restrict__ c2b,
    const float* __restrict__ l1w, const float* __restrict__ l1b,
    const float* __restrict__ l2w, const float* __restrict__ l2b,
    float* __restrict__ out)
{
    __shared__ __align__(16) float lds[LDSZ];   // 18.9 KB
    const int tid  = threadIdx.x;
    const int r    = tid & 127;          // local row 0..127
    const bool isLow = (tid & 128) == 0; // k-half (wave-uniform)
    const int R0   = blockIdx.x * RPB;   // grid exactly covers kB

    // ---- stage weights [j][k] (pre-loop region, overlaps window) ----
    if (tid < 32) {
        const int k = tid;
        float* w = lds + WSTG;
        w[0 * 32 + k] = l1w[k];
        w[1 * 32 + k] = l1w[32 + k];
        w[2 * 32 + k] = l1w[64 + k];
        w[3 * 32 + k] = l1w[96 + k];
        w[4 * 32 + k] = l1b[k];
        w[5 * 32 + k] = l2w[5 * k + 0];
        w[6 * 32 + k] = l2w[5 * k + 1];
        w[7 * 32 + k] = l2w[5 * k + 2];
        w[8 * 32 + k] = l2w[5 * k + 3];
        w[9 * 32 + k] = l2w[5 * k + 4];
    }

    // ---- coalesced input stage: 128 rows x 18 cols, flat stride 18 ----
    {
        const float* xblk = x + (size_t)R0 * 18;
        #pragma unroll
        for (int j = 0; j < 9; ++j) {
            int flat = tid + 256 * j;                // 0..2303
            lds[ISTG + flat] = xblk[flat];           // lane-contiguous
        }
    }
    __syncthreads();   // pre-loop: full barrier is fine (nothing in flight)
    float s[18];
    #pragma unroll
    for (int j = 0; j < 18; ++j) s[j] = lds[ISTG + r * 18 + j];

    // ---- weights -> 10 lane-distributed VGPRs (lane k holds weight[.][k]) ----
    const float* wl = lds + WSTG;
    const int lk = tid & 31;
    float w0 = wl[0 * 32 + lk], w1 = wl[1 * 32 + lk], w2 = wl[2 * 32 + lk];
    float w3 = wl[3 * 32 + lk], w4 = wl[4 * 32 + lk], w5 = wl[5 * 32 + lk];
    float w6 = wl[6 * 32 + lk], w7 = wl[7 * 32 + lk], w8 = wl[8 * 32 + lk];
    float w9 = wl[9 * 32 + lk];
    asm volatile("" : "+v"(w0), "+v"(w1), "+v"(w2), "+v"(w3), "+v"(w4),
                      "+v"(w5), "+v"(w6), "+v"(w7), "+v"(w8), "+v"(w9));
    // wave-uniform readlane base: 0 for half0 waves, 16 for half1 waves
    const int kbase = __builtin_amdgcn_readfirstlane((tid & 128) >> 3);
    __syncthreads();   // staging consumed; window/exchange regions live now

    const float cw10 = c1w[0], cw11 = c1w[1], cb1 = c1b[0];
    const float cw20 = c2w[0], cw21 = c2w[1], cb2 = c2b[0];
    const float b20 = l2b[0], b21 = l2b[1], b22 = l2b[2], b23 = l2b[3], b24 = l2b[4];

    // s[10] = distance
    {
        float dA = s[1] - s[3], dB = s[2] - s[4];
        s[10] = dA * dA + dB * dB;
    }

    float* lr = lds + r * PAD;                            // window row
    const int exMineOff  = XOFF + ((isLow ? 0 : 128) + r) * 5;
    const int exOtherOff = XOFF + ((isLow ? 128 : 0) + r) * 5;

    auto rec = [&](int idx, float v) { if (isLow) lr[idx] = v; };

    // flush current 128x16 window (cols [wcol, wcol+16)) coalesced.
    // lgkm-only barriers: record-writes visible before reads; reads done
    // (own lgkmcnt(0)) before any wave re-writes the window.
    auto flush16 = [&](int wcol) {
        bar_lgkm();
        const int rr = tid >> 4, cc = tid & 15;           // rr 0..15
        const float* lp = lds + rr * PAD + cc;
        float*       op = out + (size_t)(R0 + rr) * 178 + wcol + cc;
        #pragma unroll
        for (int j = 0; j < 8; ++j) {
            op[(size_t)(16 * j) * 178] = lp[16 * j * PAD];
        }
        bar_lgkm();
    };

    int wstart = 18;   // first output col held at LDS idx 0
    int nextb  = 34;   // next window boundary col

    // traj0 = s[TRAJ_IDX] at cols 18..27 -> idx 0..9
    rec(0, s[10]); rec(1, s[1]);  rec(2, s[2]); rec(3, s[3]); rec(4, s[4]);
    rec(5, s[5]);  rec(6, s[6]);  rec(7, s[7]); rec(8, s[8]); rec(9, s[17]);

    #pragma unroll 1
    for (int t = 0; t < kSteps; ++t) {
        // ---- classifier front-end on feat = s[[1,2,3,4,9,17]] ----
        float f0 = s[1], f1 = s[2], f2 = s[3], f3 = s[4], f4 = s[9], f5 = s[17];
        float h10 = relu_(cw10 * f0 + cw11 * f1 + cb1);
        float h11 = relu_(cw10 * f1 + cw11 * f2 + cb1);
        float h12 = relu_(cw10 * f2 + cw11 * f3 + cb1);
        float h13 = relu_(cw10 * f3 + cw11 * f4 + cb1);
        float h14 = relu_(cw10 * f4 + cw11 * f5 + cb1);
        float g0 = relu_(cw20 * h10 + cw21 * h11 + cb2);
        float g1 = relu_(cw20 * h11 + cw21 * h12 + cb2);
        float g2 = relu_(cw20 * h12 + cw21 * h13 + cb2);
        float g3 = relu_(cw20 * h13 + cw21 * h14 + cb2);

        // ---- this wave's 16 hidden units (readlane-broadcast weights) ----
        float p0 = isLow ? b20 : 0.f, p1 = isLow ? b21 : 0.f;
        float p2 = isLow ? b22 : 0.f, p3 = isLow ? b23 : 0.f;
        float p4 = isLow ? b24 : 0.f;
        #pragma unroll
        for (int i = 0; i < 16; ++i) {
            const int kk_ = kbase + i;
            float h = g0 * rl_(w0, kk_) + g1 * rl_(w1, kk_)
                    + g2 * rl_(w2, kk_) + g3 * rl_(w3, kk_) + rl_(w4, kk_);
            h = relu_(h);
            p0 += h * rl_(w5, kk_);
            p1 += h * rl_(w6, kk_);
            p2 += h * rl_(w7, kk_);
            p3 += h * rl_(w8, kk_);
            p4 += h * rl_(w9, kk_);
        }

        // ---- exchange partials (double-buffered, ONE lgkm barrier) ----
        {
            float* exM = lds + exMineOff + (t & 1) * 1280;
            exM[0] = p0; exM[1] = p1; exM[2] = p2; exM[3] = p3; exM[4] = p4;
            bar_lgkm();
            const float* exO = lds + exOtherOff + (t & 1) * 1280;
            p0 += exO[0]; p1 += exO[1]; p2 += exO[2];
            p3 += exO[3]; p4 += exO[4];
        }

        p0 = sigmoid_(p0); p1 = sigmoid_(p1); p2 = sigmoid_(p2);
        p3 = sigmoid_(p3); p4 = sigmoid_(p4);

        s[5] = p0; s[6] = p1; s[7] = p2; s[8] = p3; s[17] = p4;
        float a = p1 - p0, b = p2 - p0, c = p3 - p0;
        float d = p2 - p1, e = p3 - p1, f = p3 - p2;
        s[11] = a; s[12] = b; s[13] = c; s[14] = d; s[15] = e; s[16] = f;

        float dx_c = (c <= 0.f) ? 0.f  : 5.f,  st_c = (c <= 0.f) ? 0.f : 3.f;
        float dx_f = (f <= 0.f) ? 0.f  : 5.f,  st_f = (f <= 0.f) ? 2.f : 3.f;
        float dx_e = (e <= 0.f) ? -5.f : 5.f,  st_e = (e <= 0.f) ? 1.f : 3.f;
        float dx_b = (b <= 0.f) ? dx_c : dx_f, st_b = (b <= 0.f) ? st_c : st_f;
        float dx_d = (d <= 0.f) ? dx_e : dx_f, st_d = (d <= 0.f) ? st_e : st_f;
        float dx   = (a <= 0.f) ? dx_b : dx_d, st   = (a <= 0.f) ? st_b : st_d;

        s[1] += dx; s[9] = st;
        s[2] += 5.f; s[3] += 5.f; s[0] += 1.f;
        float dA = s[1] - s[3], dB = s[2] - s[4];
        s[10] = dA * dA + dB * dB;

        // ---- record s[TRAJ_IDX] into the LDS window (cols c0..c0+9) ----
        float v0 = s[10], v1 = s[1], v2 = s[2], v3 = s[3], v4 = s[4];
        float v5 = s[5],  v6 = s[6], v7 = s[7], v8 = s[8], v9 = s[17];
        const int c0 = 28 + 10 * t;
        const int kk = nextb - c0;       // uniform split point
        int off = c0 - wstart;
        if (kk >= 10) {                  // record fits current window
            rec(off + 0, v0); rec(off + 1, v1); rec(off + 2, v2);
            rec(off + 3, v3); rec(off + 4, v4); rec(off + 5, v5);
            rec(off + 6, v6); rec(off + 7, v7); rec(off + 8, v8);
            rec(off + 9, v9);
            if (kk == 10) {              // window exactly full
                flush16(wstart);
                wstart = nextb; nextb += 16;
            }
        } else {                         // record straddles the boundary
            if (kk > 0) rec(off + 0, v0);
            if (kk > 1) rec(off + 1, v1);
            if (kk > 2) rec(off + 2, v2);
            if (kk > 3) rec(off + 3, v3);
            if (kk > 4) rec(off + 4, v4);
            if (kk > 5) rec(off + 5, v5);
            if (kk > 6) rec(off + 6, v6);
            if (kk > 7) rec(off + 7, v7);
            if (kk > 8) rec(off + 8, v8);
            if (kk > 9) rec(off + 9, v9);
            flush16(wstart);
            wstart = nextb; nextb += 16;
            off = c0 - wstart;           // negative; off+j >= 0 for j >= kk
            if (kk <= 0) rec(off + 0, v0);
            if (kk <= 1) rec(off + 1, v1);
            if (kk <= 2) rec(off + 2, v2);
            if (kk <= 3) rec(off + 3, v3);
            if (kk <= 4) rec(off + 4, v4);
            if (kk <= 5) rec(off + 5, v5);
            if (kk <= 6) rec(off + 6, v6);
            if (kk <= 7) rec(off + 7, v7);
            if (kk <= 8) rec(off + 8, v8);
            if (kk <= 9) rec(off + 9, v9);
        }
    }

    // ---- final state, cols 0..17, coalesced via flat stride-18 tile ----
    bar_lgkm();
    if (isLow) {
        #pragma unroll
        for (int j = 0; j < 18; ++j) lds[r * 18 + j] = s[j];
    }
    bar_lgkm();
    #pragma unroll
    for (int j = 0; j < 9; ++j) {
        int flat = tid + 256 * j;                          // 0..2303
        int rr = (int)(((unsigned)flat * 58255u) >> 20);   // flat / 18
        int cc = flat - rr * 18;
        out[(size_t)(R0 + rr) * 178 + cc] = lds[flat];
    }
}

extern "C" void kernel_launch(void* const* d_in, const int* in_sizes, int n_in,
                              void* d_out, int out_size, void* d_ws, size_t ws_size,
                              hipStream_t stream) {
    const float* x   = (const float*)d_in[0];
    const float* c1w = (const float*)d_in[1];
    const float* c1b = (const float*)d_in[2];
    const float* c2w = (const float*)d_in[3];
    const float* c2b = (const float*)d_in[4];
    const float* l1w = (const float*)d_in[5];
    const float* l1b = (const float*)d_in[6];
    const float* l2w = (const float*)d_in[7];
    const float* l2b = (const float*)d_in[8];
    float* out = (float*)d_out;

    Program_4578435138231_kernel<<<kB / RPB, 256, 0, stream>>>(
        x, c1w, c1b, c2w, c2b, l1w, l1b, l2w, l2b, out);
}

// Round 10
// 266.420 us; speedup vs baseline: 1.1753x; 1.1753x over previous
//
#include <hip/hip_runtime.h>

// TWO LANES PER ROW: lane half=0 owns k=0..15, half=1 owns k=16..31 of the
// MLP hidden layer. Each thread keeps its 160 weight floats VGPR-resident
// (fits: ~210 VGPR < 256 cap, so the R5 spill failure mode is gone), loaded
// once before the t-loop. The k-loop is pure-VGPR FMA with ZERO memory ops;
// partials combine via __shfl_xor(.,1) (quad-perm DPP, pure VALU). Both
// lanes of a pair then carry identical state (A+B commutative -> bitwise
// same), so the serial t-loop stays lane-local.
// Rationale: R3/R4/R5 proved any per-step weight stream (ds_read, remat,
// or spill) costs ~100us regardless of occupancy; 320 floats/thread cannot
// be register-resident, so split the k-range across a lane pair.
// I/O chassis = verified round-1/3 window scheme at 128 rows/block.
//
// [R10 note] This is the verbatim round-6 kernel — the empirical best of
// the session (110.7 us/dispatch, 269 us bench). R7-R9 established that
// every alternative chassis (readlane @4 waves, wave-pair split with any
// barrier flavor) lands at 119-159 us, and the wave-scaling fit puts the
// structural floor at ~102-106 us. Locking the best point back in.

constexpr int kB     = 262144;
constexpr int kSteps = 15;
constexpr int PAD    = 33;
constexpr int RPB    = 128;            // rows per block (2 lanes per row)
constexpr int WOFF   = RPB * PAD;      // weight staging region (16B aligned)

__device__ __forceinline__ float relu_(float v) { return fmaxf(v, 0.0f); }
__device__ __forceinline__ float sigmoid_(float v) {
    return __builtin_amdgcn_rcpf(1.0f + __expf(-v));
}

__global__ __launch_bounds__(256, 2) void Program_4578435138231_kernel(
    const float* __restrict__ x,
    const float* __restrict__ c1w, const float* __restrict__ c1b,
    const float* __restrict__ c2w, const float* __restrict__ c2b,
    const float* __restrict__ l1w, const float* __restrict__ l1b,
    const float* __restrict__ l2w, const float* __restrict__ l2b,
    float* __restrict__ out)
{
    __shared__ __align__(16) float lds[RPB * PAD + 32 * 12];   // 18.4 KB
    const int tid  = threadIdx.x;
    const int rid  = tid >> 1;          // local row 0..127
    const int half = tid & 1;           // k-range half
    const int R0   = blockIdx.x * RPB;  // grid exactly covers kB

    // ---- stage packed weights: [k][ w1c0 w1c1 w1c2 w1c3 b1 w2j0..4 pad pad ]
    if (tid < 32) {
        const int k = tid;
        float* w = lds + WOFF + k * 12;
        w[0] = l1w[k];          w[1] = l1w[32 + k];
        w[2] = l1w[64 + k];     w[3] = l1w[96 + k];
        w[4] = l1b[k];
        w[5] = l2w[5 * k + 0];  w[6] = l2w[5 * k + 1];
        w[7] = l2w[5 * k + 2];  w[8] = l2w[5 * k + 3];
        w[9] = l2w[5 * k + 4];
    }

    // ---- coalesced input stage: 128 rows x 18 cols = 2304 floats ----
    {
        const float* xblk = x + (size_t)R0 * 18;
        #pragma unroll
        for (int j = 0; j < 9; ++j) {
            int flat = tid + 256 * j;                          // 0..2303
            float v  = xblk[flat];
            int r = (int)(((unsigned)flat * 58255u) >> 20);    // flat / 18
            int c = flat - r * 18;
            lds[r * PAD + c] = v;
        }
    }
    __syncthreads();
    float s[18];
    #pragma unroll
    for (int j = 0; j < 18; ++j) s[j] = lds[rid * PAD + j];

    // ---- pull THIS HALF's 16 k-columns into registers, then pin them ----
    const float* wl = lds + WOFF + half * (16 * 12);
    float wA[16], wB[16], wC[16], wD[16], wE[16];   // l1w cols 0..3, l1b
    float wF[16], wG[16], wH[16], wI[16], wJ[16];   // l2w j=0..4
    #pragma unroll
    for (int k = 0; k < 16; ++k) {
        float4 a = *reinterpret_cast<const float4*>(wl + k * 12);
        float4 b = *reinterpret_cast<const float4*>(wl + k * 12 + 4);
        float2 c = *reinterpret_cast<const float2*>(wl + k * 12 + 8);
        wA[k] = a.x; wB[k] = a.y; wC[k] = a.z; wD[k] = a.w; wE[k] = b.x;
        wF[k] = b.y; wG[k] = b.z; wH[k] = b.w; wI[k] = c.x; wJ[k] = c.y;
    }
    #pragma unroll
    for (int k = 0; k < 16; ++k) {
        asm volatile("" : "+v"(wA[k]), "+v"(wB[k]), "+v"(wC[k]), "+v"(wD[k]),
                          "+v"(wE[k]), "+v"(wF[k]), "+v"(wG[k]), "+v"(wH[k]),
                          "+v"(wI[k]), "+v"(wJ[k]));
    }
    __syncthreads();   // window region (incl. weight staging) now reusable

    const float cw10 = c1w[0], cw11 = c1w[1], cb1 = c1b[0];
    const float cw20 = c2w[0], cw21 = c2w[1], cb2 = c2b[0];
    // bias lives only in half 0's partial; half 1 starts at 0
    const float b20 = half ? 0.f : l2b[0], b21 = half ? 0.f : l2b[1];
    const float b22 = half ? 0.f : l2b[2], b23 = half ? 0.f : l2b[3];
    const float b24 = half ? 0.f : l2b[4];

    // s[10] = distance
    {
        float dA = s[1] - s[3], dB = s[2] - s[4];
        s[10] = dA * dA + dB * dB;
    }

    float* lr = lds + rid * PAD;
    auto rec = [&](int idx, float v) { if (!half) lr[idx] = v; };

    // flush current 128x32 window (cols [wcol, wcol+32)) coalesced
    auto flush32 = [&](int wcol) {
        __syncthreads();
        const int rr = tid >> 5, cc = tid & 31;    // rr 0..7
        const float* lp = lds + rr * PAD + cc;
        float*       op = out + (size_t)(R0 + rr) * 178 + wcol + cc;
        #pragma unroll
        for (int j = 0; j < 16; ++j) {
            op[(size_t)(8 * j) * 178] = lp[8 * j * PAD];
        }
        __syncthreads();
    };

    int wstart = 18;   // first output col held at LDS idx 0
    int nextb  = 50;   // next window boundary col

    // traj0 = s[TRAJ_IDX] at cols 18..27 -> idx 0..9
    rec(0, s[10]); rec(1, s[1]);  rec(2, s[2]); rec(3, s[3]); rec(4, s[4]);
    rec(5, s[5]);  rec(6, s[6]);  rec(7, s[7]); rec(8, s[8]); rec(9, s[17]);

    #pragma unroll 1
    for (int t = 0; t < kSteps; ++t) {
        // ---- classifier on feat = s[[1,2,3,4,9,17]] ----
        float f0 = s[1], f1 = s[2], f2 = s[3], f3 = s[4], f4 = s[9], f5 = s[17];
        float h10 = relu_(cw10 * f0 + cw11 * f1 + cb1);
        float h11 = relu_(cw10 * f1 + cw11 * f2 + cb1);
        float h12 = relu_(cw10 * f2 + cw11 * f3 + cb1);
        float h13 = relu_(cw10 * f3 + cw11 * f4 + cb1);
        float h14 = relu_(cw10 * f4 + cw11 * f5 + cb1);
        float g0 = relu_(cw20 * h10 + cw21 * h11 + cb2);
        float g1 = relu_(cw20 * h11 + cw21 * h12 + cb2);
        float g2 = relu_(cw20 * h12 + cw21 * h13 + cb2);
        float g3 = relu_(cw20 * h13 + cw21 * h14 + cb2);

        // ---- this half's 16 k-columns, pure-VGPR ----
        float p0 = b20, p1 = b21, p2 = b22, p3 = b23, p4 = b24;
        #pragma unroll
        for (int k = 0; k < 16; ++k) {
            float h = g0 * wA[k] + g1 * wB[k] + g2 * wC[k]
                    + g3 * wD[k] + wE[k];
            h = relu_(h);
            p0 += h * wF[k];
            p1 += h * wG[k];
            p2 += h * wH[k];
            p3 += h * wI[k];
            p4 += h * wJ[k];
        }
        // combine lane-pair partials (quad-perm DPP, pure VALU)
        p0 += __shfl_xor(p0, 1, 64);
        p1 += __shfl_xor(p1, 1, 64);
        p2 += __shfl_xor(p2, 1, 64);
        p3 += __shfl_xor(p3, 1, 64);
        p4 += __shfl_xor(p4, 1, 64);

        p0 = sigmoid_(p0); p1 = sigmoid_(p1); p2 = sigmoid_(p2);
        p3 = sigmoid_(p3); p4 = sigmoid_(p4);

        s[5] = p0; s[6] = p1; s[7] = p2; s[8] = p3; s[17] = p4;
        float a = p1 - p0, b = p2 - p0, c = p3 - p0;
        float d = p2 - p1, e = p3 - p1, f = p3 - p2;
        s[11] = a; s[12] = b; s[13] = c; s[14] = d; s[15] = e; s[16] = f;

        float dx_c = (c <= 0.f) ? 0.f  : 5.f,  st_c = (c <= 0.f) ? 0.f : 3.f;
        float dx_f = (f <= 0.f) ? 0.f  : 5.f,  st_f = (f <= 0.f) ? 2.f : 3.f;
        float dx_e = (e <= 0.f) ? -5.f : 5.f,  st_e = (e <= 0.f) ? 1.f : 3.f;
        float dx_b = (b <= 0.f) ? dx_c : dx_f, st_b = (b <= 0.f) ? st_c : st_f;
        float dx_d = (d <= 0.f) ? dx_e : dx_f, st_d = (d <= 0.f) ? st_e : st_f;
        float dx   = (a <= 0.f) ? dx_b : dx_d, st   = (a <= 0.f) ? st_b : st_d;

        s[1] += dx; s[9] = st;
        s[2] += 5.f; s[3] += 5.f; s[0] += 1.f;
        float dA = s[1] - s[3], dB = s[2] - s[4];
        s[10] = dA * dA + dB * dB;

        // ---- record s[TRAJ_IDX] into the LDS window (cols c0..c0+9) ----
        float v0 = s[10], v1 = s[1], v2 = s[2], v3 = s[3], v4 = s[4];
        float v5 = s[5],  v6 = s[6], v7 = s[7], v8 = s[8], v9 = s[17];
        const int c0 = 28 + 10 * t;
        const int kk = nextb - c0;       // uniform split point
        int off = c0 - wstart;
        if (kk >= 10) {                  // record fits current window
            rec(off + 0, v0); rec(off + 1, v1); rec(off + 2, v2);
            rec(off + 3, v3); rec(off + 4, v4); rec(off + 5, v5);
            rec(off + 6, v6); rec(off + 7, v7); rec(off + 8, v8);
            rec(off + 9, v9);
            if (kk == 10) {              // window exactly full (t = 14)
                flush32(wstart);
                wstart = nextb; nextb += 32;
            }
        } else {                         // record straddles the boundary
            if (kk > 0) rec(off + 0, v0);
            if (kk > 1) rec(off + 1, v1);
            if (kk > 2) rec(off + 2, v2);
            if (kk > 3) rec(off + 3, v3);
            if (kk > 4) rec(off + 4, v4);
            if (kk > 5) rec(off + 5, v5);
            if (kk > 6) rec(off + 6, v6);
            if (kk > 7) rec(off + 7, v7);
            if (kk > 8) rec(off + 8, v8);
            if (kk > 9) rec(off + 9, v9);
            flush32(wstart);
            wstart = nextb; nextb += 32;
            off = c0 - wstart;           // negative; off+j >= 0 for j >= kk
            if (kk <= 0) rec(off + 0, v0);
            if (kk <= 1) rec(off + 1, v1);
            if (kk <= 2) rec(off + 2, v2);
            if (kk <= 3) rec(off + 3, v3);
            if (kk <= 4) rec(off + 4, v4);
            if (kk <= 5) rec(off + 5, v5);
            if (kk <= 6) rec(off + 6, v6);
            if (kk <= 7) rec(off + 7, v7);
            if (kk <= 8) rec(off + 8, v8);
            if (kk <= 9) rec(off + 9, v9);
        }
    }

    // ---- final state, cols 0..17, coalesced via LDS ----
    __syncthreads();
    if (!half) {
        #pragma unroll
        for (int j = 0; j < 18; ++j) lr[j] = s[j];
    }
    __syncthreads();
    #pragma unroll
    for (int j = 0; j < 9; ++j) {
        int flat = tid + 256 * j;                          // 0..2303
        int r = (int)(((unsigned)flat * 58255u) >> 20);    // flat / 18
        int c = flat - r * 18;
        out[(size_t)(R0 + r) * 178 + c] = lds[r * PAD + c];
    }
}

extern "C" void kernel_launch(void* const* d_in, const int* in_sizes, int n_in,
                              void* d_out, int out_size, void* d_ws, size_t ws_size,
                              hipStream_t stream) {
    const float* x   = (const float*)d_in[0];
    const float* c1w = (const float*)d_in[1];
    const float* c1b = (const float*)d_in[2];
    const float* c2w = (const float*)d_in[3];
    const float* c2b = (const float*)d_in[4];
    const float* l1w = (const float*)d_in[5];
    const float* l1b = (const float*)d_in[6];
    const float* l2w = (const float*)d_in[7];
    const float* l2b = (const float*)d_in[8];
    float* out = (float*)d_out;

    Program_4578435138231_kernel<<<kB / RPB, 256, 0, stream>>>(
        x, c1w, c1b, c2w, c2b, l1w, l1b, l2w, l2b, out);
}

// Round 11
// 249.268 us; speedup vs baseline: 1.2561x; 1.0688x over previous
//
#include <hip/hip_runtime.h>

// R6/R10 chassis (session best, 109.8us/dispatch) + PACKED f32x2 k-loop.
// Two lanes per row: half=0 owns k=0..15, half=1 owns k=16..31. Each
// thread's 16 k-columns are processed as 8 PACKED pairs (k=2i,2i+1):
// v_pk_fma_f32 halves the k-loop instruction count (~160 -> ~80 ops/step)
// without changing thread count, occupancy, or memory behavior (R2 proved
// the compiler emits pk ops; R2's loss was wave count, not packing).
// Weight staging is planar [j][32] so a pair is a contiguous float2.
// R10 counters showed VALUBusy 63%, no scratch, weights AGPR-resident ->
// issue-bound; instruction count is the one remaining lever.
// Everything outside the k-loop is byte-for-byte the verified R10 kernel.

typedef float f32x2 __attribute__((ext_vector_type(2)));

constexpr int kB     = 262144;
constexpr int kSteps = 15;
constexpr int PAD    = 33;
constexpr int RPB    = 128;            // rows per block (2 lanes per row)
constexpr int WOFF   = RPB * PAD;      // weight staging region (even -> 8B ok)

__device__ __forceinline__ float relu_(float v) { return fmaxf(v, 0.0f); }
__device__ __forceinline__ float sigmoid_(float v) {
    return __builtin_amdgcn_rcpf(1.0f + __expf(-v));
}
__device__ __forceinline__ f32x2 splat2(float v) { return (f32x2){v, v}; }
__device__ __forceinline__ f32x2 fma2(f32x2 a, f32x2 b, f32x2 c) {
    return __builtin_elementwise_fma(a, b, c);
}
__device__ __forceinline__ f32x2 relu2(f32x2 v) {
    return __builtin_elementwise_max(v, splat2(0.0f));
}

__global__ __launch_bounds__(256, 2) void Program_4578435138231_kernel(
    const float* __restrict__ x,
    const float* __restrict__ c1w, const float* __restrict__ c1b,
    const float* __restrict__ c2w, const float* __restrict__ c2b,
    const float* __restrict__ l1w, const float* __restrict__ l1b,
    const float* __restrict__ l2w, const float* __restrict__ l2b,
    float* __restrict__ out)
{
    __shared__ __align__(16) float lds[RPB * PAD + 10 * 32];   // 18.2 KB
    const int tid  = threadIdx.x;
    const int rid  = tid >> 1;          // local row 0..127
    const int half = tid & 1;           // k-range half
    const int R0   = blockIdx.x * RPB;  // grid exactly covers kB

    // ---- stage weights PLANAR [j][k]: j=0..3 l1w rows, 4 l1b, 5..9 l2w ----
    if (tid < 32) {
        const int k = tid;
        float* w = lds + WOFF;
        w[0 * 32 + k] = l1w[k];
        w[1 * 32 + k] = l1w[32 + k];
        w[2 * 32 + k] = l1w[64 + k];
        w[3 * 32 + k] = l1w[96 + k];
        w[4 * 32 + k] = l1b[k];
        w[5 * 32 + k] = l2w[5 * k + 0];
        w[6 * 32 + k] = l2w[5 * k + 1];
        w[7 * 32 + k] = l2w[5 * k + 2];
        w[8 * 32 + k] = l2w[5 * k + 3];
        w[9 * 32 + k] = l2w[5 * k + 4];
    }

    // ---- coalesced input stage: 128 rows x 18 cols = 2304 floats ----
    {
        const float* xblk = x + (size_t)R0 * 18;
        #pragma unroll
        for (int j = 0; j < 9; ++j) {
            int flat = tid + 256 * j;                          // 0..2303
            float v  = xblk[flat];
            int r = (int)(((unsigned)flat * 58255u) >> 20);    // flat / 18
            int c = flat - r * 18;
            lds[r * PAD + c] = v;
        }
    }
    __syncthreads();
    float s[18];
    #pragma unroll
    for (int j = 0; j < 18; ++j) s[j] = lds[rid * PAD + j];

    // ---- pull THIS HALF's 16 k-columns as 8 packed pairs, then pin ----
    const float* wl = lds + WOFF;
    const int kb = half * 16;
    f32x2 wA[8], wB[8], wC[8], wD[8], wE[8];   // l1w rows 0..3, l1b
    f32x2 wF[8], wG[8], wH[8], wI[8], wJ[8];   // l2w j=0..4
    #pragma unroll
    for (int i = 0; i < 8; ++i) {
        wA[i] = *reinterpret_cast<const f32x2*>(wl + 0 * 32 + kb + 2 * i);
        wB[i] = *reinterpret_cast<const f32x2*>(wl + 1 * 32 + kb + 2 * i);
        wC[i] = *reinterpret_cast<const f32x2*>(wl + 2 * 32 + kb + 2 * i);
        wD[i] = *reinterpret_cast<const f32x2*>(wl + 3 * 32 + kb + 2 * i);
        wE[i] = *reinterpret_cast<const f32x2*>(wl + 4 * 32 + kb + 2 * i);
        wF[i] = *reinterpret_cast<const f32x2*>(wl + 5 * 32 + kb + 2 * i);
        wG[i] = *reinterpret_cast<const f32x2*>(wl + 6 * 32 + kb + 2 * i);
        wH[i] = *reinterpret_cast<const f32x2*>(wl + 7 * 32 + kb + 2 * i);
        wI[i] = *reinterpret_cast<const f32x2*>(wl + 8 * 32 + kb + 2 * i);
        wJ[i] = *reinterpret_cast<const f32x2*>(wl + 9 * 32 + kb + 2 * i);
    }
    #pragma unroll
    for (int i = 0; i < 8; ++i) {
        asm volatile("" : "+v"(wA[i]), "+v"(wB[i]), "+v"(wC[i]), "+v"(wD[i]),
                          "+v"(wE[i]), "+v"(wF[i]), "+v"(wG[i]), "+v"(wH[i]),
                          "+v"(wI[i]), "+v"(wJ[i]));
    }
    __syncthreads();   // window region (incl. weight staging) now reusable

    const float cw10 = c1w[0], cw11 = c1w[1], cb1 = c1b[0];
    const float cw20 = c2w[0], cw21 = c2w[1], cb2 = c2b[0];
    // bias lives only in half 0's partial; half 1 starts at 0
    const float b20 = half ? 0.f : l2b[0], b21 = half ? 0.f : l2b[1];
    const float b22 = half ? 0.f : l2b[2], b23 = half ? 0.f : l2b[3];
    const float b24 = half ? 0.f : l2b[4];

    // s[10] = distance
    {
        float dA = s[1] - s[3], dB = s[2] - s[4];
        s[10] = dA * dA + dB * dB;
    }

    float* lr = lds + rid * PAD;
    auto rec = [&](int idx, float v) { if (!half) lr[idx] = v; };

    // flush current 128x32 window (cols [wcol, wcol+32)) coalesced
    auto flush32 = [&](int wcol) {
        __syncthreads();
        const int rr = tid >> 5, cc = tid & 31;    // rr 0..7
        const float* lp = lds + rr * PAD + cc;
        float*       op = out + (size_t)(R0 + rr) * 178 + wcol + cc;
        #pragma unroll
        for (int j = 0; j < 16; ++j) {
            op[(size_t)(8 * j) * 178] = lp[8 * j * PAD];
        }
        __syncthreads();
    };

    int wstart = 18;   // first output col held at LDS idx 0
    int nextb  = 50;   // next window boundary col

    // traj0 = s[TRAJ_IDX] at cols 18..27 -> idx 0..9
    rec(0, s[10]); rec(1, s[1]);  rec(2, s[2]); rec(3, s[3]); rec(4, s[4]);
    rec(5, s[5]);  rec(6, s[6]);  rec(7, s[7]); rec(8, s[8]); rec(9, s[17]);

    #pragma unroll 1
    for (int t = 0; t < kSteps; ++t) {
        // ---- classifier on feat = s[[1,2,3,4,9,17]] ----
        float f0 = s[1], f1 = s[2], f2 = s[3], f3 = s[4], f4 = s[9], f5 = s[17];
        float h10 = relu_(cw10 * f0 + cw11 * f1 + cb1);
        float h11 = relu_(cw10 * f1 + cw11 * f2 + cb1);
        float h12 = relu_(cw10 * f2 + cw11 * f3 + cb1);
        float h13 = relu_(cw10 * f3 + cw11 * f4 + cb1);
        float h14 = relu_(cw10 * f4 + cw11 * f5 + cb1);
        float g0 = relu_(cw20 * h10 + cw21 * h11 + cb2);
        float g1 = relu_(cw20 * h11 + cw21 * h12 + cb2);
        float g2 = relu_(cw20 * h12 + cw21 * h13 + cb2);
        float g3 = relu_(cw20 * h13 + cw21 * h14 + cb2);

        // ---- this half's 16 k-columns as 8 PACKED pairs (v_pk_fma) ----
        const f32x2 G0 = splat2(g0), G1 = splat2(g1);
        const f32x2 G2 = splat2(g2), G3 = splat2(g3);
        f32x2 pp0 = (f32x2){b20, 0.f}, pp1 = (f32x2){b21, 0.f};
        f32x2 pp2 = (f32x2){b22, 0.f}, pp3 = (f32x2){b23, 0.f};
        f32x2 pp4 = (f32x2){b24, 0.f};
        #pragma unroll
        for (int i = 0; i < 8; ++i) {
            f32x2 hh = fma2(G0, wA[i],
                       fma2(G1, wB[i],
                       fma2(G2, wC[i],
                       fma2(G3, wD[i], wE[i]))));
            hh = relu2(hh);
            pp0 = fma2(hh, wF[i], pp0);
            pp1 = fma2(hh, wG[i], pp1);
            pp2 = fma2(hh, wH[i], pp2);
            pp3 = fma2(hh, wI[i], pp3);
            pp4 = fma2(hh, wJ[i], pp4);
        }
        float p0 = pp0.x + pp0.y, p1 = pp1.x + pp1.y, p2 = pp2.x + pp2.y;
        float p3 = pp3.x + pp3.y, p4 = pp4.x + pp4.y;

        // combine lane-pair partials (quad-perm DPP, pure VALU)
        p0 += __shfl_xor(p0, 1, 64);
        p1 += __shfl_xor(p1, 1, 64);
        p2 += __shfl_xor(p2, 1, 64);
        p3 += __shfl_xor(p3, 1, 64);
        p4 += __shfl_xor(p4, 1, 64);

        p0 = sigmoid_(p0); p1 = sigmoid_(p1); p2 = sigmoid_(p2);
        p3 = sigmoid_(p3); p4 = sigmoid_(p4);

        s[5] = p0; s[6] = p1; s[7] = p2; s[8] = p3; s[17] = p4;
        float a = p1 - p0, b = p2 - p0, c = p3 - p0;
        float d = p2 - p1, e = p3 - p1, f = p3 - p2;
        s[11] = a; s[12] = b; s[13] = c; s[14] = d; s[15] = e; s[16] = f;

        float dx_c = (c <= 0.f) ? 0.f  : 5.f,  st_c = (c <= 0.f) ? 0.f : 3.f;
        float dx_f = (f <= 0.f) ? 0.f  : 5.f,  st_f = (f <= 0.f) ? 2.f : 3.f;
        float dx_e = (e <= 0.f) ? -5.f : 5.f,  st_e = (e <= 0.f) ? 1.f : 3.f;
        float dx_b = (b <= 0.f) ? dx_c : dx_f, st_b = (b <= 0.f) ? st_c : st_f;
        float dx_d = (d <= 0.f) ? dx_e : dx_f, st_d = (d <= 0.f) ? st_e : st_f;
        float dx   = (a <= 0.f) ? dx_b : dx_d, st   = (a <= 0.f) ? st_b : st_d;

        s[1] += dx; s[9] = st;
        s[2] += 5.f; s[3] += 5.f; s[0] += 1.f;
        float dA = s[1] - s[3], dB = s[2] - s[4];
        s[10] = dA * dA + dB * dB;

        // ---- record s[TRAJ_IDX] into the LDS window (cols c0..c0+9) ----
        float v0 = s[10], v1 = s[1], v2 = s[2], v3 = s[3], v4 = s[4];
        float v5 = s[5],  v6 = s[6], v7 = s[7], v8 = s[8], v9 = s[17];
        const int c0 = 28 + 10 * t;
        const int kk = nextb - c0;       // uniform split point
        int off = c0 - wstart;
        if (kk >= 10) {                  // record fits current window
            rec(off + 0, v0); rec(off + 1, v1); rec(off + 2, v2);
            rec(off + 3, v3); rec(off + 4, v4); rec(off + 5, v5);
            rec(off + 6, v6); rec(off + 7, v7); rec(off + 8, v8);
            rec(off + 9, v9);
            if (kk == 10) {              // window exactly full (t = 14)
                flush32(wstart);
                wstart = nextb; nextb += 32;
            }
        } else {                         // record straddles the boundary
            if (kk > 0) rec(off + 0, v0);
            if (kk > 1) rec(off + 1, v1);
            if (kk > 2) rec(off + 2, v2);
            if (kk > 3) rec(off + 3, v3);
            if (kk > 4) rec(off + 4, v4);
            if (kk > 5) rec(off + 5, v5);
            if (kk > 6) rec(off + 6, v6);
            if (kk > 7) rec(off + 7, v7);
            if (kk > 8) rec(off + 8, v8);
            if (kk > 9) rec(off + 9, v9);
            flush32(wstart);
            wstart = nextb; nextb += 32;
            off = c0 - wstart;           // negative; off+j >= 0 for j >= kk
            if (kk <= 0) rec(off + 0, v0);
            if (kk <= 1) rec(off + 1, v1);
            if (kk <= 2) rec(off + 2, v2);
            if (kk <= 3) rec(off + 3, v3);
            if (kk <= 4) rec(off + 4, v4);
            if (kk <= 5) rec(off + 5, v5);
            if (kk <= 6) rec(off + 6, v6);
            if (kk <= 7) rec(off + 7, v7);
            if (kk <= 8) rec(off + 8, v8);
            if (kk <= 9) rec(off + 9, v9);
        }
    }

    // ---- final state, cols 0..17, coalesced via LDS ----
    __syncthreads();
    if (!half) {
        #pragma unroll
        for (int j = 0; j < 18; ++j) lr[j] = s[j];
    }
    __syncthreads();
    #pragma unroll
    for (int j = 0; j < 9; ++j) {
        int flat = tid + 256 * j;                          // 0..2303
        int r = (int)(((unsigned)flat * 58255u) >> 20);    // flat / 18
        int c = flat - r * 18;
        out[(size_t)(R0 + r) * 178 + c] = lds[r * PAD + c];
    }
}

extern "C" void kernel_launch(void* const* d_in, const int* in_sizes, int n_in,
                              void* d_out, int out_size, void* d_ws, size_t ws_size,
                              hipStream_t stream) {
    const float* x   = (const float*)d_in[0];
    const float* c1w = (const float*)d_in[1];
    const float* c1b = (const float*)d_in[2];
    const float* c2w = (const float*)d_in[3];
    const float* c2b = (const float*)d_in[4];
    const float* l1w = (const float*)d_in[5];
    const float* l1b = (const float*)d_in[6];
    const float* l2w = (const float*)d_in[7];
    const float* l2b = (const float*)d_in[8];
    float* out = (float*)d_out;

    Program_4578435138231_kernel<<<kB / RPB, 256, 0, stream>>>(
        x, c1w, c1b, c2w, c2b, l1w, l1b, l2w, l2b, out);
}

// Round 12
// 249.006 us; speedup vs baseline: 1.2575x; 1.0011x over previous
//
#include <hip/hip_runtime.h>

// R11 chassis (2 lanes/row, packed f32x2 k-loop) + the REMAT KILLER:
// weights are staged in an LDS region that the output window subsequently
// OVERWRITES. Cross-round evidence (R7 bank-conflicts 295K vs R6/R10/R11
// 1.87M identical; unified VGPR/AGPR file on gfx950 rules out AGPR spill;
// zero scratch) proves the compiler has been rematerializing the weight
// ds_reads into the t-loop all along — asm pins can't stop remat because
// re-loading provably-unchanged LDS is legal. Aliasing the region with the
// window makes remat ILLEGAL: after the first record write the values can
// only live in registers. launch_bounds(256,1) gives the ~210 live floats
// the full 512-VGPR budget (no spill). Occupancy falls to ~2 waves/SIMD,
// which is enough: with the LDS wall gone the loop is pure VALU with 5
// independent accumulator chains (R2's 2-wave failure was the weight
// stream, which no longer exists).

typedef float f32x2 __attribute__((ext_vector_type(2)));

constexpr int kB     = 262144;
constexpr int kSteps = 15;
constexpr int PAD    = 33;
constexpr int RPB    = 128;            // rows per block (2 lanes per row)

__device__ __forceinline__ float relu_(float v) { return fmaxf(v, 0.0f); }
__device__ __forceinline__ float sigmoid_(float v) {
    return __builtin_amdgcn_rcpf(1.0f + __expf(-v));
}
__device__ __forceinline__ f32x2 splat2(float v) { return (f32x2){v, v}; }
__device__ __forceinline__ f32x2 fma2(f32x2 a, f32x2 b, f32x2 c) {
    return __builtin_elementwise_fma(a, b, c);
}
__device__ __forceinline__ f32x2 relu2(f32x2 v) {
    return __builtin_elementwise_max(v, splat2(0.0f));
}

__global__ __launch_bounds__(256, 1) void Program_4578435138231_kernel(
    const float* __restrict__ x,
    const float* __restrict__ c1w, const float* __restrict__ c1b,
    const float* __restrict__ c2w, const float* __restrict__ c2b,
    const float* __restrict__ l1w, const float* __restrict__ l1b,
    const float* __restrict__ l2w, const float* __restrict__ l2b,
    float* __restrict__ out)
{
    __shared__ __align__(16) float lds[RPB * PAD];   // 16.9 KB — window ONLY
    const int tid  = threadIdx.x;
    const int rid  = tid >> 1;          // local row 0..127
    const int half = tid & 1;           // k-range half
    const int R0   = blockIdx.x * RPB;  // grid exactly covers kB

    // ---- stage weights PLANAR [j][32] at lds[0..320) — TEMPORARY: this
    //      region is inside the window and will be overwritten below.
    if (tid < 32) {
        const int k = tid;
        lds[0 * 32 + k] = l1w[k];
        lds[1 * 32 + k] = l1w[32 + k];
        lds[2 * 32 + k] = l1w[64 + k];
        lds[3 * 32 + k] = l1w[96 + k];
        lds[4 * 32 + k] = l1b[k];
        lds[5 * 32 + k] = l2w[5 * k + 0];
        lds[6 * 32 + k] = l2w[5 * k + 1];
        lds[7 * 32 + k] = l2w[5 * k + 2];
        lds[8 * 32 + k] = l2w[5 * k + 3];
        lds[9 * 32 + k] = l2w[5 * k + 4];
    }
    __syncthreads();

    // ---- pull THIS HALF's 16 k-columns as 8 packed pairs, then pin ----
    const int kb = half * 16;
    f32x2 wA[8], wB[8], wC[8], wD[8], wE[8];   // l1w rows 0..3, l1b
    f32x2 wF[8], wG[8], wH[8], wI[8], wJ[8];   // l2w j=0..4
    #pragma unroll
    for (int i = 0; i < 8; ++i) {
        wA[i] = *reinterpret_cast<const f32x2*>(lds + 0 * 32 + kb + 2 * i);
        wB[i] = *reinterpret_cast<const f32x2*>(lds + 1 * 32 + kb + 2 * i);
        wC[i] = *reinterpret_cast<const f32x2*>(lds + 2 * 32 + kb + 2 * i);
        wD[i] = *reinterpret_cast<const f32x2*>(lds + 3 * 32 + kb + 2 * i);
        wE[i] = *reinterpret_cast<const f32x2*>(lds + 4 * 32 + kb + 2 * i);
        wF[i] = *reinterpret_cast<const f32x2*>(lds + 5 * 32 + kb + 2 * i);
        wG[i] = *reinterpret_cast<const f32x2*>(lds + 6 * 32 + kb + 2 * i);
        wH[i] = *reinterpret_cast<const f32x2*>(lds + 7 * 32 + kb + 2 * i);
        wI[i] = *reinterpret_cast<const f32x2*>(lds + 8 * 32 + kb + 2 * i);
        wJ[i] = *reinterpret_cast<const f32x2*>(lds + 9 * 32 + kb + 2 * i);
    }
    #pragma unroll
    for (int i = 0; i < 8; ++i) {
        asm volatile("" : "+v"(wA[i]), "+v"(wB[i]), "+v"(wC[i]), "+v"(wD[i]),
                          "+v"(wE[i]), "+v"(wF[i]), "+v"(wG[i]), "+v"(wH[i]),
                          "+v"(wI[i]), "+v"(wJ[i]));
    }
    __syncthreads();   // all weight reads done — region may now be clobbered

    // ---- coalesced input stage: OVERWRITES the weight region ----
    {
        const float* xblk = x + (size_t)R0 * 18;
        #pragma unroll
        for (int j = 0; j < 9; ++j) {
            int flat = tid + 256 * j;                          // 0..2303
            float v  = xblk[flat];
            int r = (int)(((unsigned)flat * 58255u) >> 20);    // flat / 18
            int c = flat - r * 18;
            lds[r * PAD + c] = v;
        }
    }
    __syncthreads();
    float s[18];
    #pragma unroll
    for (int j = 0; j < 18; ++j) s[j] = lds[rid * PAD + j];
    __syncthreads();   // window region now reusable for records

    const float cw10 = c1w[0], cw11 = c1w[1], cb1 = c1b[0];
    const float cw20 = c2w[0], cw21 = c2w[1], cb2 = c2b[0];
    // bias lives only in half 0's partial; half 1 starts at 0
    const float b20 = half ? 0.f : l2b[0], b21 = half ? 0.f : l2b[1];
    const float b22 = half ? 0.f : l2b[2], b23 = half ? 0.f : l2b[3];
    const float b24 = half ? 0.f : l2b[4];

    // s[10] = distance
    {
        float dA = s[1] - s[3], dB = s[2] - s[4];
        s[10] = dA * dA + dB * dB;
    }

    float* lr = lds + rid * PAD;
    auto rec = [&](int idx, float v) { if (!half) lr[idx] = v; };

    // flush current 128x32 window (cols [wcol, wcol+32)) coalesced
    auto flush32 = [&](int wcol) {
        __syncthreads();
        const int rr = tid >> 5, cc = tid & 31;    // rr 0..7
        const float* lp = lds + rr * PAD + cc;
        float*       op = out + (size_t)(R0 + rr) * 178 + wcol + cc;
        #pragma unroll
        for (int j = 0; j < 16; ++j) {
            op[(size_t)(8 * j) * 178] = lp[8 * j * PAD];
        }
        __syncthreads();
    };

    int wstart = 18;   // first output col held at LDS idx 0
    int nextb  = 50;   // next window boundary col

    // traj0 = s[TRAJ_IDX] at cols 18..27 -> idx 0..9
    // (first window write — from here on, weight remat from LDS is illegal)
    rec(0, s[10]); rec(1, s[1]);  rec(2, s[2]); rec(3, s[3]); rec(4, s[4]);
    rec(5, s[5]);  rec(6, s[6]);  rec(7, s[7]); rec(8, s[8]); rec(9, s[17]);

    #pragma unroll 1
    for (int t = 0; t < kSteps; ++t) {
        // ---- classifier on feat = s[[1,2,3,4,9,17]] ----
        float f0 = s[1], f1 = s[2], f2 = s[3], f3 = s[4], f4 = s[9], f5 = s[17];
        float h10 = relu_(cw10 * f0 + cw11 * f1 + cb1);
        float h11 = relu_(cw10 * f1 + cw11 * f2 + cb1);
        float h12 = relu_(cw10 * f2 + cw11 * f3 + cb1);
        float h13 = relu_(cw10 * f3 + cw11 * f4 + cb1);
        float h14 = relu_(cw10 * f4 + cw11 * f5 + cb1);
        float g0 = relu_(cw20 * h10 + cw21 * h11 + cb2);
        float g1 = relu_(cw20 * h11 + cw21 * h12 + cb2);
        float g2 = relu_(cw20 * h12 + cw21 * h13 + cb2);
        float g3 = relu_(cw20 * h13 + cw21 * h14 + cb2);

        // ---- this half's 16 k-columns as 8 PACKED pairs (v_pk_fma) ----
        const f32x2 G0 = splat2(g0), G1 = splat2(g1);
        const f32x2 G2 = splat2(g2), G3 = splat2(g3);
        f32x2 pp0 = (f32x2){b20, 0.f}, pp1 = (f32x2){b21, 0.f};
        f32x2 pp2 = (f32x2){b22, 0.f}, pp3 = (f32x2){b23, 0.f};
        f32x2 pp4 = (f32x2){b24, 0.f};
        #pragma unroll
        for (int i = 0; i < 8; ++i) {
            f32x2 hh = fma2(G0, wA[i],
                       fma2(G1, wB[i],
                       fma2(G2, wC[i],
                       fma2(G3, wD[i], wE[i]))));
            hh = relu2(hh);
            pp0 = fma2(hh, wF[i], pp0);
            pp1 = fma2(hh, wG[i], pp1);
            pp2 = fma2(hh, wH[i], pp2);
            pp3 = fma2(hh, wI[i], pp3);
            pp4 = fma2(hh, wJ[i], pp4);
        }
        float p0 = pp0.x + pp0.y, p1 = pp1.x + pp1.y, p2 = pp2.x + pp2.y;
        float p3 = pp3.x + pp3.y, p4 = pp4.x + pp4.y;

        // combine lane-pair partials (quad-perm DPP, pure VALU)
        p0 += __shfl_xor(p0, 1, 64);
        p1 += __shfl_xor(p1, 1, 64);
        p2 += __shfl_xor(p2, 1, 64);
        p3 += __shfl_xor(p3, 1, 64);
        p4 += __shfl_xor(p4, 1, 64);

        p0 = sigmoid_(p0); p1 = sigmoid_(p1); p2 = sigmoid_(p2);
        p3 = sigmoid_(p3); p4 = sigmoid_(p4);

        s[5] = p0; s[6] = p1; s[7] = p2; s[8] = p3; s[17] = p4;
        float a = p1 - p0, b = p2 - p0, c = p3 - p0;
        float d = p2 - p1, e = p3 - p1, f = p3 - p2;
        s[11] = a; s[12] = b; s[13] = c; s[14] = d; s[15] = e; s[16] = f;

        float dx_c = (c <= 0.f) ? 0.f  : 5.f,  st_c = (c <= 0.f) ? 0.f : 3.f;
        float dx_f = (f <= 0.f) ? 0.f  : 5.f,  st_f = (f <= 0.f) ? 2.f : 3.f;
        float dx_e = (e <= 0.f) ? -5.f : 5.f,  st_e = (e <= 0.f) ? 1.f : 3.f;
        float dx_b = (b <= 0.f) ? dx_c : dx_f, st_b = (b <= 0.f) ? st_c : st_f;
        float dx_d = (d <= 0.f) ? dx_e : dx_f, st_d = (d <= 0.f) ? st_e : st_f;
        float dx   = (a <= 0.f) ? dx_b : dx_d, st   = (a <= 0.f) ? st_b : st_d;

        s[1] += dx; s[9] = st;
        s[2] += 5.f; s[3] += 5.f; s[0] += 1.f;
        float dA = s[1] - s[3], dB = s[2] - s[4];
        s[10] = dA * dA + dB * dB;

        // ---- record s[TRAJ_IDX] into the LDS window (cols c0..c0+9) ----
        float v0 = s[10], v1 = s[1], v2 = s[2], v3 = s[3], v4 = s[4];
        float v5 = s[5],  v6 = s[6], v7 = s[7], v8 = s[8], v9 = s[17];
        const int c0 = 28 + 10 * t;
        const int kk = nextb - c0;       // uniform split point
        int off = c0 - wstart;
        if (kk >= 10) {                  // record fits current window
            rec(off + 0, v0); rec(off + 1, v1); rec(off + 2, v2);
            rec(off + 3, v3); rec(off + 4, v4); rec(off + 5, v5);
            rec(off + 6, v6); rec(off + 7, v7); rec(off + 8, v8);
            rec(off + 9, v9);
            if (kk == 10) {              // window exactly full (t = 14)
                flush32(wstart);
                wstart = nextb; nextb += 32;
            }
        } else {                         // record straddles the boundary
            if (kk > 0) rec(off + 0, v0);
            if (kk > 1) rec(off + 1, v1);
            if (kk > 2) rec(off + 2, v2);
            if (kk > 3) rec(off + 3, v3);
            if (kk > 4) rec(off + 4, v4);
            if (kk > 5) rec(off + 5, v5);
            if (kk > 6) rec(off + 6, v6);
            if (kk > 7) rec(off + 7, v7);
            if (kk > 8) rec(off + 8, v8);
            if (kk > 9) rec(off + 9, v9);
            flush32(wstart);
            wstart = nextb; nextb += 32;
            off = c0 - wstart;           // negative; off+j >= 0 for j >= kk
            if (kk <= 0) rec(off + 0, v0);
            if (kk <= 1) rec(off + 1, v1);
            if (kk <= 2) rec(off + 2, v2);
            if (kk <= 3) rec(off + 3, v3);
            if (kk <= 4) rec(off + 4, v4);
            if (kk <= 5) rec(off + 5, v5);
            if (kk <= 6) rec(off + 6, v6);
            if (kk <= 7) rec(off + 7, v7);
            if (kk <= 8) rec(off + 8, v8);
            if (kk <= 9) rec(off + 9, v9);
        }
    }

    // ---- final state, cols 0..17, coalesced via LDS ----
    __syncthreads();
    if (!half) {
        #pragma unroll
        for (int j = 0; j < 18; ++j) lr[j] = s[j];
    }
    __syncthreads();
    #pragma unroll
    for (int j = 0; j < 9; ++j) {
        int flat = tid + 256 * j;                          // 0..2303
        int r = (int)(((unsigned)flat * 58255u) >> 20);    // flat / 18
        int c = flat - r * 18;
        out[(size_t)(R0 + r) * 178 + c] = lds[r * PAD + c];
    }
}

extern "C" void kernel_launch(void* const* d_in, const int* in_sizes, int n_in,
                              void* d_out, int out_size, void* d_ws, size_t ws_size,
                              hipStream_t stream) {
    const float* x   = (const float*)d_in[0];
    const float* c1w = (const float*)d_in[1];
    const float* c1b = (const float*)d_in[2];
    const float* c2w = (const float*)d_in[3];
    const float* c2b = (const float*)d_in[4];
    const float* l1w = (const float*)d_in[5];
    const float* l1b = (const float*)d_in[6];
    const float* l2w = (const float*)d_in[7];
    const float* l2b = (const float*)d_in[8];
    float* out = (float*)d_out;

    Program_4578435138231_kernel<<<kB / RPB, 256, 0, stream>>>(
        x, c1w, c1b, c2w, c2b, l1w, l1b, l2w, l2b, out);
}

// Round 13
// 247.646 us; speedup vs baseline: 1.2644x; 1.0055x over previous
//
#include <hip/hip_runtime.h>

// R12 kernel (2 lanes/row, packed f32x2 k-loop, weights staged in an LDS
// region the output window later OVERWRITES -> remat illegal) with
// occupancy restored: __launch_bounds__(256,2) -> 2 blocks/CU, 2 waves/SIMD.
// R11 (2 waves/SIMD, remat-able weights) == R12 (1 wave/SIMD, resident
// weights) == 249us bench: either R12's leaner loop was eaten by exposed
// stalls at 1 wave/SIMD, or the limit is occupancy-invariant. Register
// arithmetic (~200 VGPR weights + ~40 live = ~240 < 256) says (256,2) holds
// residency without spill — this round is a clean A/B on occupancy with
// residency fixed. FETCH jump would expose a scratch spill (revert signal).

typedef float f32x2 __attribute__((ext_vector_type(2)));

constexpr int kB     = 262144;
constexpr int kSteps = 15;
constexpr int PAD    = 33;
constexpr int RPB    = 128;            // rows per block (2 lanes per row)

__device__ __forceinline__ float relu_(float v) { return fmaxf(v, 0.0f); }
__device__ __forceinline__ float sigmoid_(float v) {
    return __builtin_amdgcn_rcpf(1.0f + __expf(-v));
}
__device__ __forceinline__ f32x2 splat2(float v) { return (f32x2){v, v}; }
__device__ __forceinline__ f32x2 fma2(f32x2 a, f32x2 b, f32x2 c) {
    return __builtin_elementwise_fma(a, b, c);
}
__device__ __forceinline__ f32x2 relu2(f32x2 v) {
    return __builtin_elementwise_max(v, splat2(0.0f));
}

__global__ __launch_bounds__(256, 2) void Program_4578435138231_kernel(
    const float* __restrict__ x,
    const float* __restrict__ c1w, const float* __restrict__ c1b,
    const float* __restrict__ c2w, const float* __restrict__ c2b,
    const float* __restrict__ l1w, const float* __restrict__ l1b,
    const float* __restrict__ l2w, const float* __restrict__ l2b,
    float* __restrict__ out)
{
    __shared__ __align__(16) float lds[RPB * PAD];   // 16.9 KB — window ONLY
    const int tid  = threadIdx.x;
    const int rid  = tid >> 1;          // local row 0..127
    const int half = tid & 1;           // k-range half
    const int R0   = blockIdx.x * RPB;  // grid exactly covers kB

    // ---- stage weights PLANAR [j][32] at lds[0..320) — TEMPORARY: this
    //      region is inside the window and will be overwritten below.
    if (tid < 32) {
        const int k = tid;
        lds[0 * 32 + k] = l1w[k];
        lds[1 * 32 + k] = l1w[32 + k];
        lds[2 * 32 + k] = l1w[64 + k];
        lds[3 * 32 + k] = l1w[96 + k];
        lds[4 * 32 + k] = l1b[k];
        lds[5 * 32 + k] = l2w[5 * k + 0];
        lds[6 * 32 + k] = l2w[5 * k + 1];
        lds[7 * 32 + k] = l2w[5 * k + 2];
        lds[8 * 32 + k] = l2w[5 * k + 3];
        lds[9 * 32 + k] = l2w[5 * k + 4];
    }
    __syncthreads();

    // ---- pull THIS HALF's 16 k-columns as 8 packed pairs, then pin ----
    const int kb = half * 16;
    f32x2 wA[8], wB[8], wC[8], wD[8], wE[8];   // l1w rows 0..3, l1b
    f32x2 wF[8], wG[8], wH[8], wI[8], wJ[8];   // l2w j=0..4
    #pragma unroll
    for (int i = 0; i < 8; ++i) {
        wA[i] = *reinterpret_cast<const f32x2*>(lds + 0 * 32 + kb + 2 * i);
        wB[i] = *reinterpret_cast<const f32x2*>(lds + 1 * 32 + kb + 2 * i);
        wC[i] = *reinterpret_cast<const f32x2*>(lds + 2 * 32 + kb + 2 * i);
        wD[i] = *reinterpret_cast<const f32x2*>(lds + 3 * 32 + kb + 2 * i);
        wE[i] = *reinterpret_cast<const f32x2*>(lds + 4 * 32 + kb + 2 * i);
        wF[i] = *reinterpret_cast<const f32x2*>(lds + 5 * 32 + kb + 2 * i);
        wG[i] = *reinterpret_cast<const f32x2*>(lds + 6 * 32 + kb + 2 * i);
        wH[i] = *reinterpret_cast<const f32x2*>(lds + 7 * 32 + kb + 2 * i);
        wI[i] = *reinterpret_cast<const f32x2*>(lds + 8 * 32 + kb + 2 * i);
        wJ[i] = *reinterpret_cast<const f32x2*>(lds + 9 * 32 + kb + 2 * i);
    }
    #pragma unroll
    for (int i = 0; i < 8; ++i) {
        asm volatile("" : "+v"(wA[i]), "+v"(wB[i]), "+v"(wC[i]), "+v"(wD[i]),
                          "+v"(wE[i]), "+v"(wF[i]), "+v"(wG[i]), "+v"(wH[i]),
                          "+v"(wI[i]), "+v"(wJ[i]));
    }
    __syncthreads();   // all weight reads done — region may now be clobbered

    // ---- coalesced input stage: OVERWRITES the weight region ----
    {
        const float* xblk = x + (size_t)R0 * 18;
        #pragma unroll
        for (int j = 0; j < 9; ++j) {
            int flat = tid + 256 * j;                          // 0..2303
            float v  = xblk[flat];
            int r = (int)(((unsigned)flat * 58255u) >> 20);    // flat / 18
            int c = flat - r * 18;
            lds[r * PAD + c] = v;
        }
    }
    __syncthreads();
    float s[18];
    #pragma unroll
    for (int j = 0; j < 18; ++j) s[j] = lds[rid * PAD + j];
    __syncthreads();   // window region now reusable for records

    const float cw10 = c1w[0], cw11 = c1w[1], cb1 = c1b[0];
    const float cw20 = c2w[0], cw21 = c2w[1], cb2 = c2b[0];
    // bias lives only in half 0's partial; half 1 starts at 0
    const float b20 = half ? 0.f : l2b[0], b21 = half ? 0.f : l2b[1];
    const float b22 = half ? 0.f : l2b[2], b23 = half ? 0.f : l2b[3];
    const float b24 = half ? 0.f : l2b[4];

    // s[10] = distance
    {
        float dA = s[1] - s[3], dB = s[2] - s[4];
        s[10] = dA * dA + dB * dB;
    }

    float* lr = lds + rid * PAD;
    auto rec = [&](int idx, float v) { if (!half) lr[idx] = v; };

    // flush current 128x32 window (cols [wcol, wcol+32)) coalesced
    auto flush32 = [&](int wcol) {
        __syncthreads();
        const int rr = tid >> 5, cc = tid & 31;    // rr 0..7
        const float* lp = lds + rr * PAD + cc;
        float*       op = out + (size_t)(R0 + rr) * 178 + wcol + cc;
        #pragma unroll
        for (int j = 0; j < 16; ++j) {
            op[(size_t)(8 * j) * 178] = lp[8 * j * PAD];
        }
        __syncthreads();
    };

    int wstart = 18;   // first output col held at LDS idx 0
    int nextb  = 50;   // next window boundary col

    // traj0 = s[TRAJ_IDX] at cols 18..27 -> idx 0..9
    // (first window write — from here on, weight remat from LDS is illegal)
    rec(0, s[10]); rec(1, s[1]);  rec(2, s[2]); rec(3, s[3]); rec(4, s[4]);
    rec(5, s[5]);  rec(6, s[6]);  rec(7, s[7]); rec(8, s[8]); rec(9, s[17]);

    #pragma unroll 1
    for (int t = 0; t < kSteps; ++t) {
        // ---- classifier on feat = s[[1,2,3,4,9,17]] ----
        float f0 = s[1], f1 = s[2], f2 = s[3], f3 = s[4], f4 = s[9], f5 = s[17];
        float h10 = relu_(cw10 * f0 + cw11 * f1 + cb1);
        float h11 = relu_(cw10 * f1 + cw11 * f2 + cb1);
        float h12 = relu_(cw10 * f2 + cw11 * f3 + cb1);
        float h13 = relu_(cw10 * f3 + cw11 * f4 + cb1);
        float h14 = relu_(cw10 * f4 + cw11 * f5 + cb1);
        float g0 = relu_(cw20 * h10 + cw21 * h11 + cb2);
        float g1 = relu_(cw20 * h11 + cw21 * h12 + cb2);
        float g2 = relu_(cw20 * h12 + cw21 * h13 + cb2);
        float g3 = relu_(cw20 * h13 + cw21 * h14 + cb2);

        // ---- this half's 16 k-columns as 8 PACKED pairs (v_pk_fma) ----
        const f32x2 G0 = splat2(g0), G1 = splat2(g1);
        const f32x2 G2 = splat2(g2), G3 = splat2(g3);
        f32x2 pp0 = (f32x2){b20, 0.f}, pp1 = (f32x2){b21, 0.f};
        f32x2 pp2 = (f32x2){b22, 0.f}, pp3 = (f32x2){b23, 0.f};
        f32x2 pp4 = (f32x2){b24, 0.f};
        #pragma unroll
        for (int i = 0; i < 8; ++i) {
            f32x2 hh = fma2(G0, wA[i],
                       fma2(G1, wB[i],
                       fma2(G2, wC[i],
                       fma2(G3, wD[i], wE[i]))));
            hh = relu2(hh);
            pp0 = fma2(hh, wF[i], pp0);
            pp1 = fma2(hh, wG[i], pp1);
            pp2 = fma2(hh, wH[i], pp2);
            pp3 = fma2(hh, wI[i], pp3);
            pp4 = fma2(hh, wJ[i], pp4);
        }
        float p0 = pp0.x + pp0.y, p1 = pp1.x + pp1.y, p2 = pp2.x + pp2.y;
        float p3 = pp3.x + pp3.y, p4 = pp4.x + pp4.y;

        // combine lane-pair partials (quad-perm DPP, pure VALU)
        p0 += __shfl_xor(p0, 1, 64);
        p1 += __shfl_xor(p1, 1, 64);
        p2 += __shfl_xor(p2, 1, 64);
        p3 += __shfl_xor(p3, 1, 64);
        p4 += __shfl_xor(p4, 1, 64);

        p0 = sigmoid_(p0); p1 = sigmoid_(p1); p2 = sigmoid_(p2);
        p3 = sigmoid_(p3); p4 = sigmoid_(p4);

        s[5] = p0; s[6] = p1; s[7] = p2; s[8] = p3; s[17] = p4;
        float a = p1 - p0, b = p2 - p0, c = p3 - p0;
        float d = p2 - p1, e = p3 - p1, f = p3 - p2;
        s[11] = a; s[12] = b; s[13] = c; s[14] = d; s[15] = e; s[16] = f;

        float dx_c = (c <= 0.f) ? 0.f  : 5.f,  st_c = (c <= 0.f) ? 0.f : 3.f;
        float dx_f = (f <= 0.f) ? 0.f  : 5.f,  st_f = (f <= 0.f) ? 2.f : 3.f;
        float dx_e = (e <= 0.f) ? -5.f : 5.f,  st_e = (e <= 0.f) ? 1.f : 3.f;
        float dx_b = (b <= 0.f) ? dx_c : dx_f, st_b = (b <= 0.f) ? st_c : st_f;
        float dx_d = (d <= 0.f) ? dx_e : dx_f, st_d = (d <= 0.f) ? st_e : st_f;
        float dx   = (a <= 0.f) ? dx_b : dx_d, st   = (a <= 0.f) ? st_b : st_d;

        s[1] += dx; s[9] = st;
        s[2] += 5.f; s[3] += 5.f; s[0] += 1.f;
        float dA = s[1] - s[3], dB = s[2] - s[4];
        s[10] = dA * dA + dB * dB;

        // ---- record s[TRAJ_IDX] into the LDS window (cols c0..c0+9) ----
        float v0 = s[10], v1 = s[1], v2 = s[2], v3 = s[3], v4 = s[4];
        float v5 = s[5],  v6 = s[6], v7 = s[7], v8 = s[8], v9 = s[17];
        const int c0 = 28 + 10 * t;
        const int kk = nextb - c0;       // uniform split point
        int off = c0 - wstart;
        if (kk >= 10) {                  // record fits current window
            rec(off + 0, v0); rec(off + 1, v1); rec(off + 2, v2);
            rec(off + 3, v3); rec(off + 4, v4); rec(off + 5, v5);
            rec(off + 6, v6); rec(off + 7, v7); rec(off + 8, v8);
            rec(off + 9, v9);
            if (kk == 10) {              // window exactly full (t = 14)
                flush32(wstart);
                wstart = nextb; nextb += 32;
            }
        } else {                         // record straddles the boundary
            if (kk > 0) rec(off + 0, v0);
            if (kk > 1) rec(off + 1, v1);
            if (kk > 2) rec(off + 2, v2);
            if (kk > 3) rec(off + 3, v3);
            if (kk > 4) rec(off + 4, v4);
            if (kk > 5) rec(off + 5, v5);
            if (kk > 6) rec(off + 6, v6);
            if (kk > 7) rec(off + 7, v7);
            if (kk > 8) rec(off + 8, v8);
            if (kk > 9) rec(off + 9, v9);
            flush32(wstart);
            wstart = nextb; nextb += 32;
            off = c0 - wstart;           // negative; off+j >= 0 for j >= kk
            if (kk <= 0) rec(off + 0, v0);
            if (kk <= 1) rec(off + 1, v1);
            if (kk <= 2) rec(off + 2, v2);
            if (kk <= 3) rec(off + 3, v3);
            if (kk <= 4) rec(off + 4, v4);
            if (kk <= 5) rec(off + 5, v5);
            if (kk <= 6) rec(off + 6, v6);
            if (kk <= 7) rec(off + 7, v7);
            if (kk <= 8) rec(off + 8, v8);
            if (kk <= 9) rec(off + 9, v9);
        }
    }

    // ---- final state, cols 0..17, coalesced via LDS ----
    __syncthreads();
    if (!half) {
        #pragma unroll
        for (int j = 0; j < 18; ++j) lr[j] = s[j];
    }
    __syncthreads();
    #pragma unroll
    for (int j = 0; j < 9; ++j) {
        int flat = tid + 256 * j;                          // 0..2303
        int r = (int)(((unsigned)flat * 58255u) >> 20);    // flat / 18
        int c = flat - r * 18;
        out[(size_t)(R0 + r) * 178 + c] = lds[r * PAD + c];
    }
}

extern "C" void kernel_launch(void* const* d_in, const int* in_sizes, int n_in,
                              void* d_out, int out_size, void* d_ws, size_t ws_size,
                              hipStream_t stream) {
    const float* x   = (const float*)d_in[0];
    const float* c1w = (const float*)d_in[1];
    const float* c1b = (const float*)d_in[2];
    const float* c2w = (const float*)d_in[3];
    const float* c2b = (const float*)d_in[4];
    const float* l1w = (const float*)d_in[5];
    const float* l1b = (const float*)d_in[6];
    const float* l2w = (const float*)d_in[7];
    const float* l2b = (const float*)d_in[8];
    float* out = (float*)d_out;

    Program_4578435138231_kernel<<<kB / RPB, 256, 0, stream>>>(
        x, c1w, c1b, c2w, c2b, l1w, l1b, l2w, l2b, out);
}